// Round 15
// baseline (350.752 us; speedup 1.0000x reference)
//
#include <hip/hip_runtime.h>
#include <hip/hip_fp16.h>
#include <cstddef>

#define N_NODES  100000
#define N_EDGES  640000
#define WIDTH    128
#define LAYERS   3
#define N_GRAPHS 64
#define ELL_K    40

#define GLOAD_LDS16(gsrc, ldst) \
  __builtin_amdgcn_global_load_lds( \
      (const __attribute__((address_space(1))) unsigned*)(gsrc), \
      (__attribute__((address_space(3))) unsigned*)(ldst), 16, 0, 0)

__device__ __forceinline__ float h2f(unsigned short h) {
  __half x; *reinterpret_cast<unsigned short*>(&x) = h;
  return __half2float(x);
}
__device__ __forceinline__ unsigned short f2h(float f) {
  __half h = __float2half_rn(f);
  return *reinterpret_cast<unsigned short*>(&h);
}

// ---------------- setup kernels ----------------

__global__ void k_init(int* __restrict__ cursor, float* __restrict__ deg,
                       float* __restrict__ ps, float* __restrict__ pas) {
  int i = blockIdx.x * blockDim.x + threadIdx.x;
  if (i < N_NODES) { cursor[i] = 0; deg[i] = 0.f; }
  if (i < N_GRAPHS) { ps[i] = 0.f; pas[i] = 0.f; }
}

// weighted in-degree only (1 atomic/edge)
__global__ void k_cd(const int* __restrict__ col, const float* __restrict__ ew,
                     float* __restrict__ deg) {
  int e = blockIdx.x * blockDim.x + threadIdx.x;
  if (e < N_EDGES) atomicAdd(&deg[col[e]], ew[e]);
}

// elementwise: dinv from deg
__global__ void k_dinv_e(const float* __restrict__ deg, float* __restrict__ dinv) {
  int v = blockIdx.x * blockDim.x + threadIdx.x;
  if (v < N_NODES) {
    float d = 2.0f + deg[v];
    dinv[v] = (d > 0.0f) ? 1.0f / sqrtf(d) : 0.0f;
  }
}

// ELL fill: packed (col, nrm); one cursor atomic + one 8B store per edge.
__global__ void k_fill_ell(const int* __restrict__ row, const int* __restrict__ col,
                           const float* __restrict__ ew, const float* __restrict__ dinv,
                           int* __restrict__ cursor, int2* __restrict__ ell) {
  int e = blockIdx.x * blockDim.x + threadIdx.x;
  if (e < N_EDGES) {
    int r = row[e], c = col[e];
    float nrm = dinv[r] * ew[e] * dinv[c];
    int slot = atomicAdd(&cursor[r], 1);
    if (slot < ELL_K) {
      int2 pk; pk.x = c; pk.y = __float_as_int(nrm);
      ell[(size_t)r * ELL_K + slot] = pk;
    }
  }
}

__device__ __forceinline__ int lbound(const int* __restrict__ batch, int key) {
  int lo = 0, hi = N_NODES;
  while (lo < hi) { int m = (lo + hi) >> 1; if (batch[m] < key) lo = m + 1; else hi = m; }
  return lo;
}

// per-graph counts + 1/max(cnt,1)
__global__ void k_cntg(const int* __restrict__ batch, int* __restrict__ cntg,
                       float* __restrict__ invc) {
  int g = threadIdx.x;
  if (g < N_GRAPHS) {
    int lb = lbound(batch, g), ub = lbound(batch, g + 1);
    int c = ub - lb;
    cntg[g] = c;
    invc[g] = 1.0f / (float)max(c, 1);
  }
}

// p[v][g] = (batch[v]==g) * invc[g]   (P^T, N x 64 fp16)
__global__ void k_pinit(const int* __restrict__ batch, const float* __restrict__ invc,
                        unsigned short* __restrict__ p) {
  const int total = N_NODES * 16;   // ushort4 count
  for (int i = blockIdx.x * blockDim.x + threadIdx.x; i < total;
       i += gridDim.x * blockDim.x) {
    int v = i >> 4, q = i & 15;
    int b = batch[v];
    ushort4 u;
    ((unsigned short*)&u)[0] = (q * 4 + 0 == b) ? f2h(invc[b]) : (unsigned short)0;
    ((unsigned short*)&u)[1] = (q * 4 + 1 == b) ? f2h(invc[b]) : (unsigned short)0;
    ((unsigned short*)&u)[2] = (q * 4 + 2 == b) ? f2h(invc[b]) : (unsigned short)0;
    ((unsigned short*)&u)[3] = (q * 4 + 3 == b) ? f2h(invc[b]) : (unsigned short)0;
    ((ushort4*)p)[i] = u;
  }
}

// colsum over y (N x 64 fp16): outv[g] += sum_v y[v][g]
// 512 blocks, ushort4 loads (wave covers 4 rows / 512B per instr),
// LDS tree over 16 row-groups, 64 atomics per block.
#define CS_BLOCKS 512
__global__ __launch_bounds__(256) void k_colsum(
    const unsigned short* __restrict__ y, float* __restrict__ outv) {
  __shared__ float4 sd[256];
  int t = threadIdx.x;
  int slot = t & 15;      // ushort4 slot: g = slot*4 .. +4
  int vrow = t >> 4;      // 16 rows in flight
  const int chunk = (N_NODES + CS_BLOCKS - 1) / CS_BLOCKS;  // 196
  int start = blockIdx.x * chunk;
  int end = min(start + chunk, N_NODES);
  float4 acc = {0.f, 0.f, 0.f, 0.f};
  for (int v = start + vrow; v < end; v += 16) {
    ushort4 u = ((const ushort4*)(y + (size_t)v * 64))[slot];
    acc.x += h2f(u.x); acc.y += h2f(u.y);
    acc.z += h2f(u.z); acc.w += h2f(u.w);
  }
  sd[t] = acc;
  __syncthreads();
  for (int off = 8; off > 0; off >>= 1) {
    if (vrow < off) {
      float4 o = sd[(vrow + off) * 16 + slot];
      acc.x += o.x; acc.y += o.y; acc.z += o.z; acc.w += o.w;
      sd[t] = acc;
    }
    __syncthreads();
  }
  if (vrow == 0) {
    atomicAdd(&outv[slot * 4 + 0], acc.x);
    atomicAdd(&outv[slot * 4 + 1], acc.y);
    atomicAdd(&outv[slot * 4 + 2], acc.z);
    atomicAdd(&outv[slot * 4 + 3], acc.w);
  }
}

// ---------------- y-chain: yOut = M^T yIn  (ELL gather, 64-wide fp16) ----------------
#define AGG_NPB 4
__global__ __launch_bounds__(256) void k_yagg(
    const unsigned short* __restrict__ yin, const int* __restrict__ cnt_a,
    const int2* __restrict__ ell, const float* __restrict__ dinv,
    unsigned short* __restrict__ yout) {
  int wave = threadIdx.x >> 6;
  int lane = threadIdx.x & 63;
  int v = blockIdx.x * AGG_NPB + wave;
  if (v >= N_NODES) return;
  int vv = __builtin_amdgcn_readfirstlane(v);
  int grp = lane >> 4;    // 0..3 edge group
  int q = lane & 15;      // ushort4 slot

  ushort4 hvu = ((const ushort4*)(yin + (size_t)vv * 64))[q];
  int cnt = cnt_a[vv];

  float4 a0 = {0,0,0,0}, a1 = {0,0,0,0}, a2 = {0,0,0,0}, a3 = {0,0,0,0};
  int2 pk = (lane < cnt) ? ell[(size_t)vv * ELL_K + lane] : make_int2(0, 0);
  int   si = pk.x;
  float swv = __int_as_float(pk.y);

  for (int base = 0; base < cnt; base += 16) {
    int e0 = base + grp;
    float w0 = __shfl(swv, e0); int i0 = __shfl(si, e0);
    ushort4 u0 = ((const ushort4*)(yin + (size_t)i0 * 64))[q];
    a0.x += w0 * h2f(u0.x); a0.y += w0 * h2f(u0.y);
    a0.z += w0 * h2f(u0.z); a0.w += w0 * h2f(u0.w);
    if (base + 4 < cnt) {
      int e1 = base + 4 + grp;
      float w1 = __shfl(swv, e1); int i1 = __shfl(si, e1);
      ushort4 u1 = ((const ushort4*)(yin + (size_t)i1 * 64))[q];
      a1.x += w1 * h2f(u1.x); a1.y += w1 * h2f(u1.y);
      a1.z += w1 * h2f(u1.z); a1.w += w1 * h2f(u1.w);
    }
    if (base + 8 < cnt) {
      int e2 = base + 8 + grp;
      int e3 = base + 12 + grp;
      float w2 = __shfl(swv, e2); int i2 = __shfl(si, e2);
      float w3 = __shfl(swv, e3); int i3 = __shfl(si, e3);
      ushort4 u2 = ((const ushort4*)(yin + (size_t)i2 * 64))[q];
      ushort4 u3 = ((const ushort4*)(yin + (size_t)i3 * 64))[q];
      a2.x += w2 * h2f(u2.x); a2.y += w2 * h2f(u2.y);
      a2.z += w2 * h2f(u2.z); a2.w += w2 * h2f(u2.w);
      a3.x += w3 * h2f(u3.x); a3.y += w3 * h2f(u3.y);
      a3.z += w3 * h2f(u3.z); a3.w += w3 * h2f(u3.w);
    }
  }

  a0.x += a1.x + a2.x + a3.x;
  a0.y += a1.y + a2.y + a3.y;
  a0.z += a1.z + a2.z + a3.z;
  a0.w += a1.w + a2.w + a3.w;
#pragma unroll
  for (int d = 16; d <= 32; d <<= 1) {
    a0.x += __shfl_xor(a0.x, d);
    a0.y += __shfl_xor(a0.y, d);
    a0.z += __shfl_xor(a0.z, d);
    a0.w += __shfl_xor(a0.w, d);
  }

  if (grp == 0) {
    float dv = dinv[vv];
    float sc = 2.0f * dv * dv;
    ushort4 r;
    r.x = f2h(a0.x + sc * h2f(hvu.x));
    r.y = f2h(a0.y + sc * h2f(hvu.y));
    r.z = f2h(a0.z + sc * h2f(hvu.z));
    r.w = f2h(a0.w + sc * h2f(hvu.w));
    ((ushort4*)(yout + (size_t)vv * 64))[q] = r;
  }
}

// ---------------- contraction: C[g][j] = sum_v Y3[v][g] * x0[v][j] ----------------
#define CT_BLOCKS 768
#define CT_NCHUNK ((N_NODES + 63) / 64)   // 1563

__global__ __launch_bounds__(256) void k_contract(
    const float* __restrict__ x0, const unsigned short* __restrict__ y3,
    float* __restrict__ part) {
  __shared__ __align__(16) float xs[64 * 128];             // 32 KB
  __shared__ __align__(16) unsigned short ysh[64 * 64];    // 8 KB fp16
  int t = threadIdx.x;
  int w = t >> 6;
  int lane = t & 63;
  int j = lane * 2;

  float2 acc[16];
#pragma unroll
  for (int i = 0; i < 16; i++) acc[i] = make_float2(0.f, 0.f);

  for (int c = blockIdx.x; c < CT_NCHUNK; c += gridDim.x) {
    int cc = min(64, N_NODES - c * 64);
    int bx = cc * 512;   // bytes of x slab
    int by = cc * 128;   // bytes of y slab (fp16)
    const char* gx = (const char*)(x0 + (size_t)c * 64 * 128);
    const char* gy = (const char*)(y3 + (size_t)c * 64 * 64);
    __syncthreads();
#pragma unroll
    for (int i = 0; i < 8; i++) {
      int off = i * 4096 + t * 16;
      if (off < bx) GLOAD_LDS16(gx + off, (char*)xs + off);
    }
#pragma unroll
    for (int i = 0; i < 2; i++) {
      int off = i * 4096 + t * 16;
      if (off < by) GLOAD_LDS16(gy + off, (char*)ysh + off);
    }
    asm volatile("s_waitcnt vmcnt(0)" ::: "memory");
    __syncthreads();

    for (int v = 0; v < cc; v++) {
      const ushort4* yr = (const ushort4*)(ysh + v * 64 + w * 16);
      ushort4 u0 = yr[0], u1 = yr[1], u2 = yr[2], u3 = yr[3];
      float2 xa = *(const float2*)(xs + v * 128 + j);
      float ys[16] = {h2f(u0.x), h2f(u0.y), h2f(u0.z), h2f(u0.w),
                      h2f(u1.x), h2f(u1.y), h2f(u1.z), h2f(u1.w),
                      h2f(u2.x), h2f(u2.y), h2f(u2.z), h2f(u2.w),
                      h2f(u3.x), h2f(u3.y), h2f(u3.z), h2f(u3.w)};
#pragma unroll
      for (int i = 0; i < 16; i++) {
        acc[i].x += ys[i] * xa.x;
        acc[i].y += ys[i] * xa.y;
      }
    }
  }

  float* dst = part + (size_t)blockIdx.x * (N_GRAPHS * WIDTH);
#pragma unroll
  for (int i = 0; i < 16; i++)
    *(float2*)(dst + (w * 16 + i) * WIDTH + j) = acc[i];
}

// ---------------- partials reduction, stage 1: 768 rows -> 12 rows ----------------
#define RC_ROWS 64
#define RC_RG (CT_BLOCKS / RC_ROWS)   // 12

__global__ __launch_bounds__(256) void k_reduce1(
    const float* __restrict__ part, float* __restrict__ part2) {
  int bid = blockIdx.x, t = threadIdx.x;
  int rg = bid >> 5, colc = bid & 31;
  int idx = colc * 256 + t;
  const float* src = part + (size_t)rg * RC_ROWS * (N_GRAPHS * WIDTH) + idx;
  float a0 = 0.f, a1 = 0.f, a2 = 0.f, a3 = 0.f;
  for (int r = 0; r < RC_ROWS; r += 4) {
    a0 += src[(size_t)(r + 0) * (N_GRAPHS * WIDTH)];
    a1 += src[(size_t)(r + 1) * (N_GRAPHS * WIDTH)];
    a2 += src[(size_t)(r + 2) * (N_GRAPHS * WIDTH)];
    a3 += src[(size_t)(r + 3) * (N_GRAPHS * WIDTH)];
  }
  part2[rg * (N_GRAPHS * WIDTH) + idx] = (a0 + a1) + (a2 + a3);
}

// O = A*B (128x128 f32); block=row, thread=col
__global__ __launch_bounds__(WIDTH) void k_mm128(
    const float* __restrict__ A, const float* __restrict__ B, float* __restrict__ O) {
  __shared__ float Ar[WIDTH];
  int r = blockIdx.x, j = threadIdx.x;
  Ar[j] = A[r * WIDTH + j];
  __syncthreads();
  float a = 0.f;
#pragma unroll 8
  for (int k = 0; k < WIDTH; k++) a += Ar[k] * B[k * WIDTH + j];
  O[r * WIDTH + j] = a;
}

// c0 = b0^T * T1 ; c1 = b1^T * W2
__global__ __launch_bounds__(WIDTH) void k_c01(
    const float* __restrict__ b0, const float* __restrict__ T1,
    const float* __restrict__ b1, const float* __restrict__ W2,
    float* __restrict__ c0, float* __restrict__ c1) {
  __shared__ float s0[WIDTH], s1v[WIDTH];
  int j = threadIdx.x;
  s0[j] = b0[j]; s1v[j] = b1[j];
  __syncthreads();
  float a0 = 0.f, a1 = 0.f;
#pragma unroll 8
  for (int k = 0; k < WIDTH; k++) {
    a0 += s0[k] * T1[k * WIDTH + j];
    a1 += s1v[k] * W2[k * WIDTH + j];
  }
  c0[j] = a0; c1[j] = a1;
}

// out[g][j]: final 12-row C-sum fused in.
__global__ __launch_bounds__(WIDTH) void k_out(
    const float* __restrict__ part2, const float* __restrict__ Wp,
    const float* __restrict__ c0, const float* __restrict__ c1,
    const float* __restrict__ ps, const float* __restrict__ pas,
    const int* __restrict__ cntg, const float* __restrict__ b2,
    float* __restrict__ out) {
  __shared__ float Cr[WIDTH];
  int g = blockIdx.x, j = threadIdx.x;
  float cv = 0.f;
#pragma unroll
  for (int rg = 0; rg < RC_RG; rg++)
    cv += part2[rg * (N_GRAPHS * WIDTH) + g * WIDTH + j];
  Cr[j] = cv;
  __syncthreads();
  float a = pas[g] * c0[j] + ps[g] * c1[j] + ((cntg[g] > 0) ? b2[j] : 0.f);
#pragma unroll 8
  for (int k = 0; k < WIDTH; k++) a += Cr[k] * Wp[k * WIDTH + j];
  out[g * WIDTH + j] = a;
}

// ---------------- launch ----------------

extern "C" void kernel_launch(void* const* d_in, const int* in_sizes, int n_in,
                              void* d_out, int out_size, void* d_ws, size_t ws_size,
                              hipStream_t stream) {
  const float* x   = (const float*)d_in[0];
  const int* row   = (const int*)d_in[1];         // edge_index[0]
  const int* col   = row + N_EDGES;               // edge_index[1]
  const float* ew  = (const float*)d_in[2];
  const int* batch = (const int*)d_in[3];
  const float* Ws  = (const float*)d_in[4];
  const float* bs  = (const float*)d_in[5];
  float* out = (float*)d_out;

  char* w = (char*)d_ws;
  float* dinv    = (float*)(w + 0);
  float* deg     = (float*)(w + 400128);
  int*   cursor  = (int*)(w + 800256);
  int*   cntg    = (int*)(w + 1200384);
  float* invc    = (float*)(w + 1200640);
  float* ps      = (float*)(w + 1200896);
  float* pas     = (float*)(w + 1201152);
  float* T1      = (float*)(w + 1201408);
  float* Wp      = (float*)(w + 1266944);
  float* c0      = (float*)(w + 1332480);
  float* c1      = (float*)(w + 1332992);
  int2*  ell     = (int2*)(w + 1333504);     // 32 MB
  float* part    = (float*)(w + 33554432);   // 25.2 MB
  float* part2   = (float*)(w + 58720256);   // 12*8192*4
  unsigned short* yA = (unsigned short*)(w + 59113472);  // N*64 fp16
  unsigned short* yB = (unsigned short*)(w + 71913472);  // N*64 fp16

  int nb_n = (N_NODES + 255) / 256;
  int nb_e = (N_EDGES + 255) / 256;

  k_init  <<<nb_n, 256, 0, stream>>>(cursor, deg, ps, pas);
  k_cd    <<<nb_e, 256, 0, stream>>>(col, ew, deg);
  k_dinv_e<<<nb_n, 256, 0, stream>>>(deg, dinv);
  k_fill_ell<<<nb_e, 256, 0, stream>>>(row, col, ew, dinv, cursor, ell);

  k_cntg <<<1, 64, 0, stream>>>(batch, cntg, invc);
  k_pinit<<<2048, 256, 0, stream>>>(batch, invc, yA);

  int nb_y = (N_NODES + AGG_NPB - 1) / AGG_NPB;
  k_yagg  <<<nb_y, 256, 0, stream>>>(yA, cursor, ell, dinv, yB);  // y1
  k_colsum<<<CS_BLOCKS, 256, 0, stream>>>(yB, ps);                // ps = P M 1
  k_yagg  <<<nb_y, 256, 0, stream>>>(yB, cursor, ell, dinv, yA);  // y2
  k_colsum<<<CS_BLOCKS, 256, 0, stream>>>(yA, pas);               // pas = P M^2 1
  k_yagg  <<<nb_y, 256, 0, stream>>>(yA, cursor, ell, dinv, yB);  // y3

  k_mm128<<<WIDTH, WIDTH, 0, stream>>>(Ws + 1 * WIDTH * WIDTH, Ws + 2 * WIDTH * WIDTH, T1);
  k_mm128<<<WIDTH, WIDTH, 0, stream>>>(Ws + 0 * WIDTH * WIDTH, T1, Wp);
  k_c01  <<<1, WIDTH, 0, stream>>>(bs, T1, bs + WIDTH, Ws + 2 * WIDTH * WIDTH, c0, c1);

  k_contract<<<CT_BLOCKS, 256, 0, stream>>>(x, yB, part);
  k_reduce1 <<<RC_RG * 32, 256, 0, stream>>>(part, part2);
  k_out     <<<N_GRAPHS, WIDTH, 0, stream>>>(part2, Wp, c0, c1, ps, pas, cntg,
                                             bs + 2 * WIDTH, out);
}

// Round 16
// 288.001 us; speedup vs baseline: 1.2179x; 1.2179x over previous
//
#include <hip/hip_runtime.h>
#include <hip/hip_fp16.h>
#include <cstddef>

#define N_NODES  100000
#define N_EDGES  640000
#define WIDTH    128
#define LAYERS   3
#define N_GRAPHS 64
#define ELL_K    40

#define GLOAD_LDS16(gsrc, ldst) \
  __builtin_amdgcn_global_load_lds( \
      (const __attribute__((address_space(1))) unsigned*)(gsrc), \
      (__attribute__((address_space(3))) unsigned*)(ldst), 16, 0, 0)

__device__ __forceinline__ float h2f(unsigned short h) {
  __half x; *reinterpret_cast<unsigned short*>(&x) = h;
  return __half2float(x);
}
__device__ __forceinline__ unsigned short f2h(float f) {
  __half h = __float2half_rn(f);
  return *reinterpret_cast<unsigned short*>(&h);
}

// ---------------- setup kernels ----------------

__global__ void k_init(int* __restrict__ cursor, float* __restrict__ deg) {
  int i = blockIdx.x * blockDim.x + threadIdx.x;
  if (i < N_NODES) { cursor[i] = 0; deg[i] = 0.f; }
}

// weighted in-degree only (1 atomic/edge)
__global__ void k_cd(const int* __restrict__ col, const float* __restrict__ ew,
                     float* __restrict__ deg) {
  int e = blockIdx.x * blockDim.x + threadIdx.x;
  if (e < N_EDGES) atomicAdd(&deg[col[e]], ew[e]);
}

// elementwise: dinv from deg
__global__ void k_dinv_e(const float* __restrict__ deg, float* __restrict__ dinv) {
  int v = blockIdx.x * blockDim.x + threadIdx.x;
  if (v < N_NODES) {
    float d = 2.0f + deg[v];
    dinv[v] = (d > 0.0f) ? 1.0f / sqrtf(d) : 0.0f;
  }
}

// ELL fill: packed (col, nrm); one cursor atomic + one 8B store per edge.
__global__ void k_fill_ell(const int* __restrict__ row, const int* __restrict__ col,
                           const float* __restrict__ ew, const float* __restrict__ dinv,
                           int* __restrict__ cursor, int2* __restrict__ ell) {
  int e = blockIdx.x * blockDim.x + threadIdx.x;
  if (e < N_EDGES) {
    int r = row[e], c = col[e];
    float nrm = dinv[r] * ew[e] * dinv[c];
    int slot = atomicAdd(&cursor[r], 1);
    if (slot < ELL_K) {
      int2 pk; pk.x = c; pk.y = __float_as_int(nrm);
      ell[(size_t)r * ELL_K + slot] = pk;
    }
  }
}

__device__ __forceinline__ int lbound(const int* __restrict__ batch, int key) {
  int lo = 0, hi = N_NODES;
  while (lo < hi) { int m = (lo + hi) >> 1; if (batch[m] < key) lo = m + 1; else hi = m; }
  return lo;
}

// per-graph counts + 1/max(cnt,1)
__global__ void k_cntg(const int* __restrict__ batch, int* __restrict__ cntg,
                       float* __restrict__ invc) {
  int g = threadIdx.x;
  if (g < N_GRAPHS) {
    int lb = lbound(batch, g), ub = lbound(batch, g + 1);
    int c = ub - lb;
    cntg[g] = c;
    invc[g] = 1.0f / (float)max(c, 1);
  }
}

// p[v][g] = (batch[v]==g) * invc[g]   (P^T, N x 64 fp16)
__global__ void k_pinit(const int* __restrict__ batch, const float* __restrict__ invc,
                        unsigned short* __restrict__ p) {
  const int total = N_NODES * 16;   // ushort4 count
  for (int i = blockIdx.x * blockDim.x + threadIdx.x; i < total;
       i += gridDim.x * blockDim.x) {
    int v = i >> 4, q = i & 15;
    int b = batch[v];
    ushort4 u;
    ((unsigned short*)&u)[0] = (q * 4 + 0 == b) ? f2h(invc[b]) : (unsigned short)0;
    ((unsigned short*)&u)[1] = (q * 4 + 1 == b) ? f2h(invc[b]) : (unsigned short)0;
    ((unsigned short*)&u)[2] = (q * 4 + 2 == b) ? f2h(invc[b]) : (unsigned short)0;
    ((unsigned short*)&u)[3] = (q * 4 + 3 == b) ? f2h(invc[b]) : (unsigned short)0;
    ((ushort4*)p)[i] = u;
  }
}

// colsum over y (N x 64 fp16): per-block partial -> plain stores (NO atomics;
// r14/r15 lesson: 8-32K atomics onto 4 cache lines = ~50us serialization tail)
#define CS_BLOCKS 512
__global__ __launch_bounds__(256) void k_colsum(
    const unsigned short* __restrict__ y, float* __restrict__ partc) {
  __shared__ float4 sd[256];
  int t = threadIdx.x;
  int slot = t & 15;      // ushort4 slot: g = slot*4 .. +4
  int vrow = t >> 4;      // 16 rows in flight
  const int chunk = (N_NODES + CS_BLOCKS - 1) / CS_BLOCKS;  // 196
  int start = blockIdx.x * chunk;
  int end = min(start + chunk, N_NODES);
  float4 acc = {0.f, 0.f, 0.f, 0.f};
  for (int v = start + vrow; v < end; v += 16) {
    ushort4 u = ((const ushort4*)(y + (size_t)v * 64))[slot];
    acc.x += h2f(u.x); acc.y += h2f(u.y);
    acc.z += h2f(u.z); acc.w += h2f(u.w);
  }
  sd[t] = acc;
  __syncthreads();
  for (int off = 8; off > 0; off >>= 1) {
    if (vrow < off) {
      float4 o = sd[(vrow + off) * 16 + slot];
      acc.x += o.x; acc.y += o.y; acc.z += o.z; acc.w += o.w;
      sd[t] = acc;
    }
    __syncthreads();
  }
  if (vrow == 0)
    ((float4*)(partc + (size_t)blockIdx.x * 64))[slot] = acc;
}

// reduce colsum partials: block 0 -> ps (from csA), block 1 -> pas (from csB)
__global__ __launch_bounds__(256) void k_cs2(
    const float* __restrict__ csA, const float* __restrict__ csB,
    float* __restrict__ ps, float* __restrict__ pas) {
  __shared__ float sd[256];
  const float* src = (blockIdx.x == 0) ? csA : csB;
  float* dst = (blockIdx.x == 0) ? ps : pas;
  int t = threadIdx.x;
  int g = t & 63, c = t >> 6;   // 4 row-chunks of 128
  float a = 0.f;
  for (int r = c * 128; r < (c + 1) * 128; r++) a += src[r * 64 + g];
  sd[t] = a;
  __syncthreads();
  if (t < 128) sd[t] += sd[t + 128];
  __syncthreads();
  if (t < 64) dst[t] = sd[t] + sd[t + 64];
}

// ---------------- y-chain: yOut = M^T yIn  (ELL gather, 64-wide fp16) ----------------
#define AGG_NPB 4
__global__ __launch_bounds__(256) void k_yagg(
    const unsigned short* __restrict__ yin, const int* __restrict__ cnt_a,
    const int2* __restrict__ ell, const float* __restrict__ dinv,
    unsigned short* __restrict__ yout) {
  int wave = threadIdx.x >> 6;
  int lane = threadIdx.x & 63;
  int v = blockIdx.x * AGG_NPB + wave;
  if (v >= N_NODES) return;
  int vv = __builtin_amdgcn_readfirstlane(v);
  int grp = lane >> 4;    // 0..3 edge group
  int q = lane & 15;      // ushort4 slot

  ushort4 hvu = ((const ushort4*)(yin + (size_t)vv * 64))[q];
  int cnt = cnt_a[vv];

  float4 a0 = {0,0,0,0}, a1 = {0,0,0,0}, a2 = {0,0,0,0}, a3 = {0,0,0,0};
  int2 pk = (lane < cnt) ? ell[(size_t)vv * ELL_K + lane] : make_int2(0, 0);
  int   si = pk.x;
  float swv = __int_as_float(pk.y);

  for (int base = 0; base < cnt; base += 16) {
    int e0 = base + grp;
    float w0 = __shfl(swv, e0); int i0 = __shfl(si, e0);
    ushort4 u0 = ((const ushort4*)(yin + (size_t)i0 * 64))[q];
    a0.x += w0 * h2f(u0.x); a0.y += w0 * h2f(u0.y);
    a0.z += w0 * h2f(u0.z); a0.w += w0 * h2f(u0.w);
    if (base + 4 < cnt) {
      int e1 = base + 4 + grp;
      float w1 = __shfl(swv, e1); int i1 = __shfl(si, e1);
      ushort4 u1 = ((const ushort4*)(yin + (size_t)i1 * 64))[q];
      a1.x += w1 * h2f(u1.x); a1.y += w1 * h2f(u1.y);
      a1.z += w1 * h2f(u1.z); a1.w += w1 * h2f(u1.w);
    }
    if (base + 8 < cnt) {
      int e2 = base + 8 + grp;
      int e3 = base + 12 + grp;
      float w2 = __shfl(swv, e2); int i2 = __shfl(si, e2);
      float w3 = __shfl(swv, e3); int i3 = __shfl(si, e3);
      ushort4 u2 = ((const ushort4*)(yin + (size_t)i2 * 64))[q];
      ushort4 u3 = ((const ushort4*)(yin + (size_t)i3 * 64))[q];
      a2.x += w2 * h2f(u2.x); a2.y += w2 * h2f(u2.y);
      a2.z += w2 * h2f(u2.z); a2.w += w2 * h2f(u2.w);
      a3.x += w3 * h2f(u3.x); a3.y += w3 * h2f(u3.y);
      a3.z += w3 * h2f(u3.z); a3.w += w3 * h2f(u3.w);
    }
  }

  a0.x += a1.x + a2.x + a3.x;
  a0.y += a1.y + a2.y + a3.y;
  a0.z += a1.z + a2.z + a3.z;
  a0.w += a1.w + a2.w + a3.w;
#pragma unroll
  for (int d = 16; d <= 32; d <<= 1) {
    a0.x += __shfl_xor(a0.x, d);
    a0.y += __shfl_xor(a0.y, d);
    a0.z += __shfl_xor(a0.z, d);
    a0.w += __shfl_xor(a0.w, d);
  }

  if (grp == 0) {
    float dv = dinv[vv];
    float sc = 2.0f * dv * dv;
    ushort4 r;
    r.x = f2h(a0.x + sc * h2f(hvu.x));
    r.y = f2h(a0.y + sc * h2f(hvu.y));
    r.z = f2h(a0.z + sc * h2f(hvu.z));
    r.w = f2h(a0.w + sc * h2f(hvu.w));
    ((ushort4*)(yout + (size_t)vv * 64))[q] = r;
  }
}

// ---------------- contraction: C[g][j] = sum_v Y3[v][g] * x0[v][j] ----------------
#define CT_BLOCKS 768
#define CT_NCHUNK ((N_NODES + 63) / 64)   // 1563

__global__ __launch_bounds__(256) void k_contract(
    const float* __restrict__ x0, const unsigned short* __restrict__ y3,
    float* __restrict__ part) {
  __shared__ __align__(16) float xs[64 * 128];             // 32 KB
  __shared__ __align__(16) unsigned short ysh[64 * 64];    // 8 KB fp16
  int t = threadIdx.x;
  int w = t >> 6;
  int lane = t & 63;
  int j = lane * 2;

  float2 acc[16];
#pragma unroll
  for (int i = 0; i < 16; i++) acc[i] = make_float2(0.f, 0.f);

  for (int c = blockIdx.x; c < CT_NCHUNK; c += gridDim.x) {
    int cc = min(64, N_NODES - c * 64);
    int bx = cc * 512;   // bytes of x slab
    int by = cc * 128;   // bytes of y slab (fp16)
    const char* gx = (const char*)(x0 + (size_t)c * 64 * 128);
    const char* gy = (const char*)(y3 + (size_t)c * 64 * 64);
    __syncthreads();
#pragma unroll
    for (int i = 0; i < 8; i++) {
      int off = i * 4096 + t * 16;
      if (off < bx) GLOAD_LDS16(gx + off, (char*)xs + off);
    }
#pragma unroll
    for (int i = 0; i < 2; i++) {
      int off = i * 4096 + t * 16;
      if (off < by) GLOAD_LDS16(gy + off, (char*)ysh + off);
    }
    asm volatile("s_waitcnt vmcnt(0)" ::: "memory");
    __syncthreads();

    for (int v = 0; v < cc; v++) {
      const ushort4* yr = (const ushort4*)(ysh + v * 64 + w * 16);
      ushort4 u0 = yr[0], u1 = yr[1], u2 = yr[2], u3 = yr[3];
      float2 xa = *(const float2*)(xs + v * 128 + j);
      float ys[16] = {h2f(u0.x), h2f(u0.y), h2f(u0.z), h2f(u0.w),
                      h2f(u1.x), h2f(u1.y), h2f(u1.z), h2f(u1.w),
                      h2f(u2.x), h2f(u2.y), h2f(u2.z), h2f(u2.w),
                      h2f(u3.x), h2f(u3.y), h2f(u3.z), h2f(u3.w)};
#pragma unroll
      for (int i = 0; i < 16; i++) {
        acc[i].x += ys[i] * xa.x;
        acc[i].y += ys[i] * xa.y;
      }
    }
  }

  float* dst = part + (size_t)blockIdx.x * (N_GRAPHS * WIDTH);
#pragma unroll
  for (int i = 0; i < 16; i++)
    *(float2*)(dst + (w * 16 + i) * WIDTH + j) = acc[i];
}

// ---------------- partials reduction, stage 1: 768 rows -> 12 rows ----------------
#define RC_ROWS 64
#define RC_RG (CT_BLOCKS / RC_ROWS)   // 12

__global__ __launch_bounds__(256) void k_reduce1(
    const float* __restrict__ part, float* __restrict__ part2) {
  int bid = blockIdx.x, t = threadIdx.x;
  int rg = bid >> 5, colc = bid & 31;
  int idx = colc * 256 + t;
  const float* src = part + (size_t)rg * RC_ROWS * (N_GRAPHS * WIDTH) + idx;
  float a0 = 0.f, a1 = 0.f, a2 = 0.f, a3 = 0.f;
  for (int r = 0; r < RC_ROWS; r += 4) {
    a0 += src[(size_t)(r + 0) * (N_GRAPHS * WIDTH)];
    a1 += src[(size_t)(r + 1) * (N_GRAPHS * WIDTH)];
    a2 += src[(size_t)(r + 2) * (N_GRAPHS * WIDTH)];
    a3 += src[(size_t)(r + 3) * (N_GRAPHS * WIDTH)];
  }
  part2[rg * (N_GRAPHS * WIDTH) + idx] = (a0 + a1) + (a2 + a3);
}

// O = A*B (128x128 f32); block=row, thread=col
__global__ __launch_bounds__(WIDTH) void k_mm128(
    const float* __restrict__ A, const float* __restrict__ B, float* __restrict__ O) {
  __shared__ float Ar[WIDTH];
  int r = blockIdx.x, j = threadIdx.x;
  Ar[j] = A[r * WIDTH + j];
  __syncthreads();
  float a = 0.f;
#pragma unroll 8
  for (int k = 0; k < WIDTH; k++) a += Ar[k] * B[k * WIDTH + j];
  O[r * WIDTH + j] = a;
}

// c0 = b0^T * T1 ; c1 = b1^T * W2
__global__ __launch_bounds__(WIDTH) void k_c01(
    const float* __restrict__ b0, const float* __restrict__ T1,
    const float* __restrict__ b1, const float* __restrict__ W2,
    float* __restrict__ c0, float* __restrict__ c1) {
  __shared__ float s0[WIDTH], s1v[WIDTH];
  int j = threadIdx.x;
  s0[j] = b0[j]; s1v[j] = b1[j];
  __syncthreads();
  float a0 = 0.f, a1 = 0.f;
#pragma unroll 8
  for (int k = 0; k < WIDTH; k++) {
    a0 += s0[k] * T1[k * WIDTH + j];
    a1 += s1v[k] * W2[k * WIDTH + j];
  }
  c0[j] = a0; c1[j] = a1;
}

// out[g][j]: final 12-row C-sum fused in.
__global__ __launch_bounds__(WIDTH) void k_out(
    const float* __restrict__ part2, const float* __restrict__ Wp,
    const float* __restrict__ c0, const float* __restrict__ c1,
    const float* __restrict__ ps, const float* __restrict__ pas,
    const int* __restrict__ cntg, const float* __restrict__ b2,
    float* __restrict__ out) {
  __shared__ float Cr[WIDTH];
  int g = blockIdx.x, j = threadIdx.x;
  float cv = 0.f;
#pragma unroll
  for (int rg = 0; rg < RC_RG; rg++)
    cv += part2[rg * (N_GRAPHS * WIDTH) + g * WIDTH + j];
  Cr[j] = cv;
  __syncthreads();
  float a = pas[g] * c0[j] + ps[g] * c1[j] + ((cntg[g] > 0) ? b2[j] : 0.f);
#pragma unroll 8
  for (int k = 0; k < WIDTH; k++) a += Cr[k] * Wp[k * WIDTH + j];
  out[g * WIDTH + j] = a;
}

// ---------------- launch ----------------

extern "C" void kernel_launch(void* const* d_in, const int* in_sizes, int n_in,
                              void* d_out, int out_size, void* d_ws, size_t ws_size,
                              hipStream_t stream) {
  const float* x   = (const float*)d_in[0];
  const int* row   = (const int*)d_in[1];         // edge_index[0]
  const int* col   = row + N_EDGES;               // edge_index[1]
  const float* ew  = (const float*)d_in[2];
  const int* batch = (const int*)d_in[3];
  const float* Ws  = (const float*)d_in[4];
  const float* bs  = (const float*)d_in[5];
  float* out = (float*)d_out;

  char* w = (char*)d_ws;
  float* dinv    = (float*)(w + 0);
  float* deg     = (float*)(w + 400128);
  int*   cursor  = (int*)(w + 800256);
  int*   cntg    = (int*)(w + 1200384);
  float* invc    = (float*)(w + 1200640);
  float* ps      = (float*)(w + 1200896);
  float* pas     = (float*)(w + 1201152);
  float* T1      = (float*)(w + 1201408);
  float* Wp      = (float*)(w + 1266944);
  float* c0      = (float*)(w + 1332480);
  float* c1      = (float*)(w + 1332992);
  int2*  ell     = (int2*)(w + 1333504);     // 32 MB
  float* part    = (float*)(w + 33554432);   // 25.2 MB
  float* part2   = (float*)(w + 58720256);   // 12*8192*4
  unsigned short* yA = (unsigned short*)(w + 59113472);  // N*64 fp16
  unsigned short* yB = (unsigned short*)(w + 71913472);  // N*64 fp16, ends 84713472
  float* csA     = (float*)(w + 84713472);   // 512*64 f32
  float* csB     = (float*)(w + 84844544);   // 512*64 f32, ends 84975616

  int nb_n = (N_NODES + 255) / 256;
  int nb_e = (N_EDGES + 255) / 256;

  k_init  <<<nb_n, 256, 0, stream>>>(cursor, deg);
  k_cd    <<<nb_e, 256, 0, stream>>>(col, ew, deg);
  k_dinv_e<<<nb_n, 256, 0, stream>>>(deg, dinv);
  k_fill_ell<<<nb_e, 256, 0, stream>>>(row, col, ew, dinv, cursor, ell);

  k_cntg <<<1, 64, 0, stream>>>(batch, cntg, invc);
  k_pinit<<<2048, 256, 0, stream>>>(batch, invc, yA);

  int nb_y = (N_NODES + AGG_NPB - 1) / AGG_NPB;
  k_yagg  <<<nb_y, 256, 0, stream>>>(yA, cursor, ell, dinv, yB);  // y1
  k_colsum<<<CS_BLOCKS, 256, 0, stream>>>(yB, csA);               // -> ps partials
  k_yagg  <<<nb_y, 256, 0, stream>>>(yB, cursor, ell, dinv, yA);  // y2
  k_colsum<<<CS_BLOCKS, 256, 0, stream>>>(yA, csB);               // -> pas partials
  k_yagg  <<<nb_y, 256, 0, stream>>>(yA, cursor, ell, dinv, yB);  // y3

  k_cs2  <<<2, 256, 0, stream>>>(csA, csB, ps, pas);
  k_mm128<<<WIDTH, WIDTH, 0, stream>>>(Ws + 1 * WIDTH * WIDTH, Ws + 2 * WIDTH * WIDTH, T1);
  k_mm128<<<WIDTH, WIDTH, 0, stream>>>(Ws + 0 * WIDTH * WIDTH, T1, Wp);
  k_c01  <<<1, WIDTH, 0, stream>>>(bs, T1, bs + WIDTH, Ws + 2 * WIDTH * WIDTH, c0, c1);

  k_contract<<<CT_BLOCKS, 256, 0, stream>>>(x, yB, part);
  k_reduce1 <<<RC_RG * 32, 256, 0, stream>>>(part, part2);
  k_out     <<<N_GRAPHS, WIDTH, 0, stream>>>(part2, Wp, c0, c1, ps, pas, cntg,
                                             bs + 2 * WIDTH, out);
}

// Round 17
// 278.786 us; speedup vs baseline: 1.2581x; 1.0331x over previous
//
#include <hip/hip_runtime.h>
#include <hip/hip_fp16.h>
#include <cstddef>

#define N_NODES  100000
#define N_EDGES  640000
#define WIDTH    128
#define LAYERS   3
#define N_GRAPHS 64
#define ELL_K    40

__device__ __forceinline__ float h2f(unsigned short h) {
  __half x; *reinterpret_cast<unsigned short*>(&x) = h;
  return __half2float(x);
}
__device__ __forceinline__ unsigned short f2h(float f) {
  __half h = __float2half_rn(f);
  return *reinterpret_cast<unsigned short*>(&h);
}

// ---------------- setup kernels ----------------

__global__ void k_init(int* __restrict__ cursor, float* __restrict__ deg) {
  int i = blockIdx.x * blockDim.x + threadIdx.x;
  if (i < N_NODES) { cursor[i] = 0; deg[i] = 0.f; }
}

// merged edge pass: weighted in-degree + ELL fill with RAW edge weight
// (z-space algebra removes dinv from edge weights -> no dependency on deg)
__global__ void k_fill_cd(const int* __restrict__ row, const int* __restrict__ col,
                          const float* __restrict__ ew,
                          int* __restrict__ cursor, float* __restrict__ deg,
                          int2* __restrict__ ell) {
  int e = blockIdx.x * blockDim.x + threadIdx.x;
  if (e < N_EDGES) {
    int r = row[e], c = col[e];
    float w = ew[e];
    atomicAdd(&deg[c], w);
    int slot = atomicAdd(&cursor[r], 1);
    if (slot < ELL_K) {
      int2 pk; pk.x = c; pk.y = __float_as_int(w);
      ell[(size_t)r * ELL_K + slot] = pk;
    }
  }
}

// elementwise: dinv = rsqrt(d), d2 = 1/d, sq = sqrt(d) (= 1/dinv)
__global__ void k_dinv_e(const float* __restrict__ deg, float* __restrict__ dinv,
                         float* __restrict__ d2, float* __restrict__ sq) {
  int v = blockIdx.x * blockDim.x + threadIdx.x;
  if (v < N_NODES) {
    float d = 2.0f + deg[v];
    float di = (d > 0.0f) ? 1.0f / sqrtf(d) : 0.0f;
    dinv[v] = di;
    d2[v] = di * di;
    sq[v] = sqrtf(d);
  }
}

__device__ __forceinline__ int lbound(const int* __restrict__ batch, int key) {
  int lo = 0, hi = N_NODES;
  while (lo < hi) { int m = (lo + hi) >> 1; if (batch[m] < key) lo = m + 1; else hi = m; }
  return lo;
}

// per-graph counts + 1/max(cnt,1)
__global__ void k_cntg(const int* __restrict__ batch, int* __restrict__ cntg,
                       float* __restrict__ invc) {
  int g = threadIdx.x;
  if (g < N_GRAPHS) {
    int lb = lbound(batch, g), ub = lbound(batch, g + 1);
    int c = ub - lb;
    cntg[g] = c;
    invc[g] = 1.0f / (float)max(c, 1);
  }
}

// z0[v][g] = (batch[v]==g) * invc[g] * dinv[v]   (z-space P^T, N x 64 fp16)
__global__ void k_pinit(const int* __restrict__ batch, const float* __restrict__ invc,
                        const float* __restrict__ dinv, unsigned short* __restrict__ p) {
  const int total = N_NODES * 16;   // ushort4 count
  for (int i = blockIdx.x * blockDim.x + threadIdx.x; i < total;
       i += gridDim.x * blockDim.x) {
    int v = i >> 4, q = i & 15;
    int b = batch[v];
    unsigned short val = f2h(invc[b] * dinv[v]);
    ushort4 u;
    ((unsigned short*)&u)[0] = (q * 4 + 0 == b) ? val : (unsigned short)0;
    ((unsigned short*)&u)[1] = (q * 4 + 1 == b) ? val : (unsigned short)0;
    ((unsigned short*)&u)[2] = (q * 4 + 2 == b) ? val : (unsigned short)0;
    ((unsigned short*)&u)[3] = (q * 4 + 3 == b) ? val : (unsigned short)0;
    ((ushort4*)p)[i] = u;
  }
}

// weighted colsum over z (N x 64 fp16): partc[b][g] = sum_v z[v][g]*sq[v]
// plain stores, NO atomics (r15 lesson: hot-address atomics = 50us tail)
#define CS_BLOCKS 512
__global__ __launch_bounds__(256) void k_colsum(
    const unsigned short* __restrict__ y, const float* __restrict__ sq,
    float* __restrict__ partc) {
  __shared__ float4 sd[256];
  int t = threadIdx.x;
  int slot = t & 15;      // ushort4 slot
  int vrow = t >> 4;      // 16 rows in flight
  const int chunk = (N_NODES + CS_BLOCKS - 1) / CS_BLOCKS;  // 196
  int start = blockIdx.x * chunk;
  int end = min(start + chunk, N_NODES);
  float4 acc = {0.f, 0.f, 0.f, 0.f};
  for (int v = start + vrow; v < end; v += 16) {
    ushort4 u = ((const ushort4*)(y + (size_t)v * 64))[slot];
    float rd = sq[v];
    acc.x += h2f(u.x) * rd; acc.y += h2f(u.y) * rd;
    acc.z += h2f(u.z) * rd; acc.w += h2f(u.w) * rd;
  }
  sd[t] = acc;
  __syncthreads();
  for (int off = 8; off > 0; off >>= 1) {
    if (vrow < off) {
      float4 o = sd[(vrow + off) * 16 + slot];
      acc.x += o.x; acc.y += o.y; acc.z += o.z; acc.w += o.w;
      sd[t] = acc;
    }
    __syncthreads();
  }
  if (vrow == 0)
    ((float4*)(partc + (size_t)blockIdx.x * 64))[slot] = acc;
}

// reduce colsum partials: block 0 -> ps (csA), block 1 -> pas (csB)
__global__ __launch_bounds__(256) void k_cs2(
    const float* __restrict__ csA, const float* __restrict__ csB,
    float* __restrict__ ps, float* __restrict__ pas) {
  __shared__ float sd[256];
  const float* src = (blockIdx.x == 0) ? csA : csB;
  float* dst = (blockIdx.x == 0) ? ps : pas;
  int t = threadIdx.x;
  int g = t & 63, c = t >> 6;   // 4 row-chunks of 128
  float a = 0.f;
  for (int r = c * 128; r < (c + 1) * 128; r++) a += src[r * 64 + g];
  sd[t] = a;
  __syncthreads();
  if (t < 128) sd[t] += sd[t + 128];
  __syncthreads();
  if (t < 64) dst[t] = sd[t] + sd[t + 64];
}

// ---------------- y-chain (z-space): zout = scale * (sum w*z[col] + 2*zin) ----------------
// scale = d2 (passes 1,2: stays in z-space) or dinv (pass 3: emits true y3)
#define AGG_NPB 4
__global__ __launch_bounds__(256) void k_yagg(
    const unsigned short* __restrict__ yin, const int* __restrict__ cnt_a,
    const int2* __restrict__ ell, const float* __restrict__ scale,
    unsigned short* __restrict__ yout) {
  int wave = threadIdx.x >> 6;
  int lane = threadIdx.x & 63;
  int v = blockIdx.x * AGG_NPB + wave;
  if (v >= N_NODES) return;
  int vv = __builtin_amdgcn_readfirstlane(v);
  int grp = lane >> 4;    // 0..3 edge group
  int q = lane & 15;      // ushort4 slot

  ushort4 hvu = ((const ushort4*)(yin + (size_t)vv * 64))[q];
  int cnt = cnt_a[vv];

  float4 a0 = {0,0,0,0}, a1 = {0,0,0,0}, a2 = {0,0,0,0}, a3 = {0,0,0,0};
  int2 pk = (lane < cnt) ? ell[(size_t)vv * ELL_K + lane] : make_int2(0, 0);
  int   si = pk.x;
  float swv = __int_as_float(pk.y);

  for (int base = 0; base < cnt; base += 16) {
    int e0 = base + grp;
    float w0 = __shfl(swv, e0); int i0 = __shfl(si, e0);
    ushort4 u0 = ((const ushort4*)(yin + (size_t)i0 * 64))[q];
    a0.x += w0 * h2f(u0.x); a0.y += w0 * h2f(u0.y);
    a0.z += w0 * h2f(u0.z); a0.w += w0 * h2f(u0.w);
    if (base + 4 < cnt) {
      int e1 = base + 4 + grp;
      float w1 = __shfl(swv, e1); int i1 = __shfl(si, e1);
      ushort4 u1 = ((const ushort4*)(yin + (size_t)i1 * 64))[q];
      a1.x += w1 * h2f(u1.x); a1.y += w1 * h2f(u1.y);
      a1.z += w1 * h2f(u1.z); a1.w += w1 * h2f(u1.w);
    }
    if (base + 8 < cnt) {
      int e2 = base + 8 + grp;
      int e3 = base + 12 + grp;
      float w2 = __shfl(swv, e2); int i2 = __shfl(si, e2);
      float w3 = __shfl(swv, e3); int i3 = __shfl(si, e3);
      ushort4 u2 = ((const ushort4*)(yin + (size_t)i2 * 64))[q];
      ushort4 u3 = ((const ushort4*)(yin + (size_t)i3 * 64))[q];
      a2.x += w2 * h2f(u2.x); a2.y += w2 * h2f(u2.y);
      a2.z += w2 * h2f(u2.z); a2.w += w2 * h2f(u2.w);
      a3.x += w3 * h2f(u3.x); a3.y += w3 * h2f(u3.y);
      a3.z += w3 * h2f(u3.z); a3.w += w3 * h2f(u3.w);
    }
  }

  a0.x += a1.x + a2.x + a3.x;
  a0.y += a1.y + a2.y + a3.y;
  a0.z += a1.z + a2.z + a3.z;
  a0.w += a1.w + a2.w + a3.w;
#pragma unroll
  for (int d = 16; d <= 32; d <<= 1) {
    a0.x += __shfl_xor(a0.x, d);
    a0.y += __shfl_xor(a0.y, d);
    a0.z += __shfl_xor(a0.z, d);
    a0.w += __shfl_xor(a0.w, d);
  }

  if (grp == 0) {
    float sc = scale[vv];
    ushort4 r;
    r.x = f2h(sc * (a0.x + 2.0f * h2f(hvu.x)));
    r.y = f2h(sc * (a0.y + 2.0f * h2f(hvu.y)));
    r.z = f2h(sc * (a0.z + 2.0f * h2f(hvu.z)));
    r.w = f2h(sc * (a0.w + 2.0f * h2f(hvu.w)));
    ((ushort4*)(yout + (size_t)vv * 64))[q] = r;
  }
}

// ---------------- contraction v3: C[g][j] = sum_v Y3[v][g] * x0[v][j] ----------------
// NO LDS: x float4 coalesced (8x L2-hit reuse), y b64 wave-broadcast.
// 1024 blocks x 4 waves, no barriers -> high occupancy, v-unrolled x2.
#define CT_BLOCKS 1024

__global__ __launch_bounds__(256) void k_contract(
    const float* __restrict__ x0, const unsigned short* __restrict__ y3,
    float* __restrict__ part) {
  int t = threadIdx.x;
  int jq = t & 31;       // float4 slot in 128-wide x row
  int gg = t >> 5;       // 8 groups x 8 g's

  float4 acc[8];
#pragma unroll
  for (int i = 0; i < 8; i++) acc[i] = make_float4(0.f, 0.f, 0.f, 0.f);

  int v = blockIdx.x;
  for (; v + CT_BLOCKS < N_NODES; v += 2 * CT_BLOCKS) {
    int v2 = v + CT_BLOCKS;
    float4 xa = ((const float4*)(x0 + (size_t)v * WIDTH))[jq];
    float4 xb = ((const float4*)(x0 + (size_t)v2 * WIDTH))[jq];
    const ushort4* ya = (const ushort4*)(y3 + (size_t)v * 64 + gg * 8);
    const ushort4* yb = (const ushort4*)(y3 + (size_t)v2 * 64 + gg * 8);
    ushort4 ua0 = ya[0], ua1 = ya[1];
    ushort4 ub0 = yb[0], ub1 = yb[1];
    float yas[8] = {h2f(ua0.x), h2f(ua0.y), h2f(ua0.z), h2f(ua0.w),
                    h2f(ua1.x), h2f(ua1.y), h2f(ua1.z), h2f(ua1.w)};
    float ybs[8] = {h2f(ub0.x), h2f(ub0.y), h2f(ub0.z), h2f(ub0.w),
                    h2f(ub1.x), h2f(ub1.y), h2f(ub1.z), h2f(ub1.w)};
#pragma unroll
    for (int i = 0; i < 8; i++) {
      acc[i].x += yas[i] * xa.x; acc[i].y += yas[i] * xa.y;
      acc[i].z += yas[i] * xa.z; acc[i].w += yas[i] * xa.w;
    }
#pragma unroll
    for (int i = 0; i < 8; i++) {
      acc[i].x += ybs[i] * xb.x; acc[i].y += ybs[i] * xb.y;
      acc[i].z += ybs[i] * xb.z; acc[i].w += ybs[i] * xb.w;
    }
  }
  if (v < N_NODES) {
    float4 xa = ((const float4*)(x0 + (size_t)v * WIDTH))[jq];
    const ushort4* ya = (const ushort4*)(y3 + (size_t)v * 64 + gg * 8);
    ushort4 ua0 = ya[0], ua1 = ya[1];
    float yas[8] = {h2f(ua0.x), h2f(ua0.y), h2f(ua0.z), h2f(ua0.w),
                    h2f(ua1.x), h2f(ua1.y), h2f(ua1.z), h2f(ua1.w)};
#pragma unroll
    for (int i = 0; i < 8; i++) {
      acc[i].x += yas[i] * xa.x; acc[i].y += yas[i] * xa.y;
      acc[i].z += yas[i] * xa.z; acc[i].w += yas[i] * xa.w;
    }
  }

  float* dst = part + (size_t)blockIdx.x * (N_GRAPHS * WIDTH);
#pragma unroll
  for (int i = 0; i < 8; i++)
    *(float4*)(dst + (gg * 8 + i) * WIDTH + jq * 4) = acc[i];
}

// ---------------- partials reduction: 1024 rows -> 16 rows ----------------
#define RC_ROWS 64
#define RC_RG (CT_BLOCKS / RC_ROWS)   // 16

__global__ __launch_bounds__(256) void k_reduce1(
    const float* __restrict__ part, float* __restrict__ part2) {
  int bid = blockIdx.x, t = threadIdx.x;
  int rg = bid >> 5, colc = bid & 31;
  int idx = colc * 256 + t;
  const float* src = part + (size_t)rg * RC_ROWS * (N_GRAPHS * WIDTH) + idx;
  float a0 = 0.f, a1 = 0.f, a2 = 0.f, a3 = 0.f;
  for (int r = 0; r < RC_ROWS; r += 4) {
    a0 += src[(size_t)(r + 0) * (N_GRAPHS * WIDTH)];
    a1 += src[(size_t)(r + 1) * (N_GRAPHS * WIDTH)];
    a2 += src[(size_t)(r + 2) * (N_GRAPHS * WIDTH)];
    a3 += src[(size_t)(r + 3) * (N_GRAPHS * WIDTH)];
  }
  part2[rg * (N_GRAPHS * WIDTH) + idx] = (a0 + a1) + (a2 + a3);
}

// O = A*B (128x128 f32); block=row, thread=col
__global__ __launch_bounds__(WIDTH) void k_mm128(
    const float* __restrict__ A, const float* __restrict__ B, float* __restrict__ O) {
  __shared__ float Ar[WIDTH];
  int r = blockIdx.x, j = threadIdx.x;
  Ar[j] = A[r * WIDTH + j];
  __syncthreads();
  float a = 0.f;
#pragma unroll 8
  for (int k = 0; k < WIDTH; k++) a += Ar[k] * B[k * WIDTH + j];
  O[r * WIDTH + j] = a;
}

// c0 = b0^T * T1 ; c1 = b1^T * W2
__global__ __launch_bounds__(WIDTH) void k_c01(
    const float* __restrict__ b0, const float* __restrict__ T1,
    const float* __restrict__ b1, const float* __restrict__ W2,
    float* __restrict__ c0, float* __restrict__ c1) {
  __shared__ float s0[WIDTH], s1v[WIDTH];
  int j = threadIdx.x;
  s0[j] = b0[j]; s1v[j] = b1[j];
  __syncthreads();
  float a0 = 0.f, a1 = 0.f;
#pragma unroll 8
  for (int k = 0; k < WIDTH; k++) {
    a0 += s0[k] * T1[k * WIDTH + j];
    a1 += s1v[k] * W2[k * WIDTH + j];
  }
  c0[j] = a0; c1[j] = a1;
}

// out[g][j]: final 16-row C-sum fused in.
__global__ __launch_bounds__(WIDTH) void k_out(
    const float* __restrict__ part2, const float* __restrict__ Wp,
    const float* __restrict__ c0, const float* __restrict__ c1,
    const float* __restrict__ ps, const float* __restrict__ pas,
    const int* __restrict__ cntg, const float* __restrict__ b2,
    float* __restrict__ out) {
  __shared__ float Cr[WIDTH];
  int g = blockIdx.x, j = threadIdx.x;
  float cv = 0.f;
#pragma unroll
  for (int rg = 0; rg < RC_RG; rg++)
    cv += part2[rg * (N_GRAPHS * WIDTH) + g * WIDTH + j];
  Cr[j] = cv;
  __syncthreads();
  float a = pas[g] * c0[j] + ps[g] * c1[j] + ((cntg[g] > 0) ? b2[j] : 0.f);
#pragma unroll 8
  for (int k = 0; k < WIDTH; k++) a += Cr[k] * Wp[k * WIDTH + j];
  out[g * WIDTH + j] = a;
}

// ---------------- launch ----------------

extern "C" void kernel_launch(void* const* d_in, const int* in_sizes, int n_in,
                              void* d_out, int out_size, void* d_ws, size_t ws_size,
                              hipStream_t stream) {
  const float* x   = (const float*)d_in[0];
  const int* row   = (const int*)d_in[1];         // edge_index[0]
  const int* col   = row + N_EDGES;               // edge_index[1]
  const float* ew  = (const float*)d_in[2];
  const int* batch = (const int*)d_in[3];
  const float* Ws  = (const float*)d_in[4];
  const float* bs  = (const float*)d_in[5];
  float* out = (float*)d_out;

  char* w = (char*)d_ws;
  float* dinv    = (float*)(w + 0);
  float* d2      = (float*)(w + 400128);
  float* sq      = (float*)(w + 800256);
  float* deg     = (float*)(w + 1200384);
  int*   cursor  = (int*)(w + 1600512);
  int*   cntg    = (int*)(w + 2000640);
  float* invc    = (float*)(w + 2000896);
  float* ps      = (float*)(w + 2001152);
  float* pas     = (float*)(w + 2001408);
  float* T1      = (float*)(w + 2001664);
  float* Wp      = (float*)(w + 2067200);
  float* c0      = (float*)(w + 2132736);
  float* c1      = (float*)(w + 2133248);
  int2*  ell     = (int2*)(w + 2133760);     // 32 MB -> ends 34133760
  float* part    = (float*)(w + 34133760);   // 1024*8192*4 = 33.55 MB -> 67688192
  float* part2   = (float*)(w + 67688192);   // 16*8192*4 -> 68212480
  unsigned short* yA = (unsigned short*)(w + 68212480);  // N*64 fp16 -> 81012480
  unsigned short* yB = (unsigned short*)(w + 81012480);  // N*64 fp16 -> 93812480
  float* csA     = (float*)(w + 93812480);   // 512*64 f32
  float* csB     = (float*)(w + 93943552);   // ends 94074624

  int nb_n = (N_NODES + 255) / 256;
  int nb_e = (N_EDGES + 255) / 256;

  k_init   <<<nb_n, 256, 0, stream>>>(cursor, deg);
  k_fill_cd<<<nb_e, 256, 0, stream>>>(row, col, ew, cursor, deg, ell);
  k_dinv_e <<<nb_n, 256, 0, stream>>>(deg, dinv, d2, sq);

  k_cntg <<<1, 64, 0, stream>>>(batch, cntg, invc);
  k_pinit<<<2048, 256, 0, stream>>>(batch, invc, dinv, yA);

  int nb_y = (N_NODES + AGG_NPB - 1) / AGG_NPB;
  k_yagg  <<<nb_y, 256, 0, stream>>>(yA, cursor, ell, d2, yB);    // z1
  k_colsum<<<CS_BLOCKS, 256, 0, stream>>>(yB, sq, csA);           // -> ps partials
  k_yagg  <<<nb_y, 256, 0, stream>>>(yB, cursor, ell, d2, yA);    // z2
  k_colsum<<<CS_BLOCKS, 256, 0, stream>>>(yA, sq, csB);           // -> pas partials
  k_yagg  <<<nb_y, 256, 0, stream>>>(yA, cursor, ell, dinv, yB);  // y3 (true y)

  k_cs2  <<<2, 256, 0, stream>>>(csA, csB, ps, pas);
  k_mm128<<<WIDTH, WIDTH, 0, stream>>>(Ws + 1 * WIDTH * WIDTH, Ws + 2 * WIDTH * WIDTH, T1);
  k_mm128<<<WIDTH, WIDTH, 0, stream>>>(Ws + 0 * WIDTH * WIDTH, T1, Wp);
  k_c01  <<<1, WIDTH, 0, stream>>>(bs, T1, bs + WIDTH, Ws + 2 * WIDTH * WIDTH, c0, c1);

  k_contract<<<CT_BLOCKS, 256, 0, stream>>>(x, yB, part);
  k_reduce1 <<<RC_RG * 32, 256, 0, stream>>>(part, part2);
  k_out     <<<N_GRAPHS, WIDTH, 0, stream>>>(part2, Wp, c0, c1, ps, pas, cntg,
                                             bs + 2 * WIDTH, out);
}

// Round 18
// 274.112 us; speedup vs baseline: 1.2796x; 1.0170x over previous
//
#include <hip/hip_runtime.h>
#include <hip/hip_fp16.h>
#include <cstddef>

#define N_NODES  100000
#define N_EDGES  640000
#define WIDTH    128
#define LAYERS   3
#define N_GRAPHS 64
#define ELL_K    40

#define GLOAD_LDS16(gsrc, ldst) \
  __builtin_amdgcn_global_load_lds( \
      (const __attribute__((address_space(1))) unsigned*)(gsrc), \
      (__attribute__((address_space(3))) unsigned*)(ldst), 16, 0, 0)

__device__ __forceinline__ float h2f(unsigned short h) {
  __half x; *reinterpret_cast<unsigned short*>(&x) = h;
  return __half2float(x);
}
__device__ __forceinline__ unsigned short f2h(float f) {
  __half h = __float2half_rn(f);
  return *reinterpret_cast<unsigned short*>(&h);
}

// ---------------- setup kernels ----------------

__global__ void k_init(int* __restrict__ cursor, float* __restrict__ deg) {
  int i = blockIdx.x * blockDim.x + threadIdx.x;
  if (i < N_NODES) { cursor[i] = 0; deg[i] = 0.f; }
}

// merged edge pass: weighted in-degree + ELL fill with RAW edge weight
__global__ void k_fill_cd(const int* __restrict__ row, const int* __restrict__ col,
                          const float* __restrict__ ew,
                          int* __restrict__ cursor, float* __restrict__ deg,
                          int2* __restrict__ ell) {
  int e = blockIdx.x * blockDim.x + threadIdx.x;
  if (e < N_EDGES) {
    int r = row[e], c = col[e];
    float w = ew[e];
    atomicAdd(&deg[c], w);
    int slot = atomicAdd(&cursor[r], 1);
    if (slot < ELL_K) {
      int2 pk; pk.x = c; pk.y = __float_as_int(w);
      ell[(size_t)r * ELL_K + slot] = pk;
    }
  }
}

// elementwise: dinv = rsqrt(d), d2 = 1/d, sq = sqrt(d)
__global__ void k_dinv_e(const float* __restrict__ deg, float* __restrict__ dinv,
                         float* __restrict__ d2, float* __restrict__ sq) {
  int v = blockIdx.x * blockDim.x + threadIdx.x;
  if (v < N_NODES) {
    float d = 2.0f + deg[v];
    float di = (d > 0.0f) ? 1.0f / sqrtf(d) : 0.0f;
    dinv[v] = di;
    d2[v] = di * di;
    sq[v] = sqrtf(d);
  }
}

__device__ __forceinline__ int lbound(const int* __restrict__ batch, int key) {
  int lo = 0, hi = N_NODES;
  while (lo < hi) { int m = (lo + hi) >> 1; if (batch[m] < key) lo = m + 1; else hi = m; }
  return lo;
}

// per-graph counts + 1/max(cnt,1)
__global__ void k_cntg(const int* __restrict__ batch, int* __restrict__ cntg,
                       float* __restrict__ invc) {
  int g = threadIdx.x;
  if (g < N_GRAPHS) {
    int lb = lbound(batch, g), ub = lbound(batch, g + 1);
    int c = ub - lb;
    cntg[g] = c;
    invc[g] = 1.0f / (float)max(c, 1);
  }
}

// z0[v][g] = (batch[v]==g) * invc[g] * dinv[v]   (z-space P^T, N x 64 fp16)
__global__ void k_pinit(const int* __restrict__ batch, const float* __restrict__ invc,
                        const float* __restrict__ dinv, unsigned short* __restrict__ p) {
  const int total = N_NODES * 16;   // ushort4 count
  for (int i = blockIdx.x * blockDim.x + threadIdx.x; i < total;
       i += gridDim.x * blockDim.x) {
    int v = i >> 4, q = i & 15;
    int b = batch[v];
    unsigned short val = f2h(invc[b] * dinv[v]);
    ushort4 u;
    ((unsigned short*)&u)[0] = (q * 4 + 0 == b) ? val : (unsigned short)0;
    ((unsigned short*)&u)[1] = (q * 4 + 1 == b) ? val : (unsigned short)0;
    ((unsigned short*)&u)[2] = (q * 4 + 2 == b) ? val : (unsigned short)0;
    ((unsigned short*)&u)[3] = (q * 4 + 3 == b) ? val : (unsigned short)0;
    ((ushort4*)p)[i] = u;
  }
}

// weighted colsum over z (N x 64 fp16): partc[b][g] = sum_v z[v][g]*sq[v]
// plain stores, NO atomics (r15 lesson: hot-address atomics = 50us tail)
#define CS_BLOCKS 512
__global__ __launch_bounds__(256) void k_colsum(
    const unsigned short* __restrict__ y, const float* __restrict__ sq,
    float* __restrict__ partc) {
  __shared__ float4 sd[256];
  int t = threadIdx.x;
  int slot = t & 15;      // ushort4 slot
  int vrow = t >> 4;      // 16 rows in flight
  const int chunk = (N_NODES + CS_BLOCKS - 1) / CS_BLOCKS;  // 196
  int start = blockIdx.x * chunk;
  int end = min(start + chunk, N_NODES);
  float4 acc = {0.f, 0.f, 0.f, 0.f};
  for (int v = start + vrow; v < end; v += 16) {
    ushort4 u = ((const ushort4*)(y + (size_t)v * 64))[slot];
    float rd = sq[v];
    acc.x += h2f(u.x) * rd; acc.y += h2f(u.y) * rd;
    acc.z += h2f(u.z) * rd; acc.w += h2f(u.w) * rd;
  }
  sd[t] = acc;
  __syncthreads();
  for (int off = 8; off > 0; off >>= 1) {
    if (vrow < off) {
      float4 o = sd[(vrow + off) * 16 + slot];
      acc.x += o.x; acc.y += o.y; acc.z += o.z; acc.w += o.w;
      sd[t] = acc;
    }
    __syncthreads();
  }
  if (vrow == 0)
    ((float4*)(partc + (size_t)blockIdx.x * 64))[slot] = acc;
}

// reduce colsum partials: block 0 -> ps (csA), block 1 -> pas (csB)
__global__ __launch_bounds__(256) void k_cs2(
    const float* __restrict__ csA, const float* __restrict__ csB,
    float* __restrict__ ps, float* __restrict__ pas) {
  __shared__ float sd[256];
  const float* src = (blockIdx.x == 0) ? csA : csB;
  float* dst = (blockIdx.x == 0) ? ps : pas;
  int t = threadIdx.x;
  int g = t & 63, c = t >> 6;   // 4 row-chunks of 128
  float a = 0.f;
  for (int r = c * 128; r < (c + 1) * 128; r++) a += src[r * 64 + g];
  sd[t] = a;
  __syncthreads();
  if (t < 128) sd[t] += sd[t + 128];
  __syncthreads();
  if (t < 64) dst[t] = sd[t] + sd[t + 64];
}

// ---------------- y-chain (z-space): zout = scale * (sum w*z[col] + 2*zin) ----------------
#define AGG_NPB 4
__global__ __launch_bounds__(256) void k_yagg(
    const unsigned short* __restrict__ yin, const int* __restrict__ cnt_a,
    const int2* __restrict__ ell, const float* __restrict__ scale,
    unsigned short* __restrict__ yout) {
  int wave = threadIdx.x >> 6;
  int lane = threadIdx.x & 63;
  int v = blockIdx.x * AGG_NPB + wave;
  if (v >= N_NODES) return;
  int vv = __builtin_amdgcn_readfirstlane(v);
  int grp = lane >> 4;    // 0..3 edge group
  int q = lane & 15;      // ushort4 slot

  ushort4 hvu = ((const ushort4*)(yin + (size_t)vv * 64))[q];
  int cnt = cnt_a[vv];

  float4 a0 = {0,0,0,0}, a1 = {0,0,0,0}, a2 = {0,0,0,0}, a3 = {0,0,0,0};
  int2 pk = (lane < cnt) ? ell[(size_t)vv * ELL_K + lane] : make_int2(0, 0);
  int   si = pk.x;
  float swv = __int_as_float(pk.y);

  for (int base = 0; base < cnt; base += 16) {
    int e0 = base + grp;
    float w0 = __shfl(swv, e0); int i0 = __shfl(si, e0);
    ushort4 u0 = ((const ushort4*)(yin + (size_t)i0 * 64))[q];
    a0.x += w0 * h2f(u0.x); a0.y += w0 * h2f(u0.y);
    a0.z += w0 * h2f(u0.z); a0.w += w0 * h2f(u0.w);
    if (base + 4 < cnt) {
      int e1 = base + 4 + grp;
      float w1 = __shfl(swv, e1); int i1 = __shfl(si, e1);
      ushort4 u1 = ((const ushort4*)(yin + (size_t)i1 * 64))[q];
      a1.x += w1 * h2f(u1.x); a1.y += w1 * h2f(u1.y);
      a1.z += w1 * h2f(u1.z); a1.w += w1 * h2f(u1.w);
    }
    if (base + 8 < cnt) {
      int e2 = base + 8 + grp;
      int e3 = base + 12 + grp;
      float w2 = __shfl(swv, e2); int i2 = __shfl(si, e2);
      float w3 = __shfl(swv, e3); int i3 = __shfl(si, e3);
      ushort4 u2 = ((const ushort4*)(yin + (size_t)i2 * 64))[q];
      ushort4 u3 = ((const ushort4*)(yin + (size_t)i3 * 64))[q];
      a2.x += w2 * h2f(u2.x); a2.y += w2 * h2f(u2.y);
      a2.z += w2 * h2f(u2.z); a2.w += w2 * h2f(u2.w);
      a3.x += w3 * h2f(u3.x); a3.y += w3 * h2f(u3.y);
      a3.z += w3 * h2f(u3.z); a3.w += w3 * h2f(u3.w);
    }
  }

  a0.x += a1.x + a2.x + a3.x;
  a0.y += a1.y + a2.y + a3.y;
  a0.z += a1.z + a2.z + a3.z;
  a0.w += a1.w + a2.w + a3.w;
#pragma unroll
  for (int d = 16; d <= 32; d <<= 1) {
    a0.x += __shfl_xor(a0.x, d);
    a0.y += __shfl_xor(a0.y, d);
    a0.z += __shfl_xor(a0.z, d);
    a0.w += __shfl_xor(a0.w, d);
  }

  if (grp == 0) {
    float sc = scale[vv];
    ushort4 r;
    r.x = f2h(sc * (a0.x + 2.0f * h2f(hvu.x)));
    r.y = f2h(sc * (a0.y + 2.0f * h2f(hvu.y)));
    r.z = f2h(sc * (a0.z + 2.0f * h2f(hvu.z)));
    r.w = f2h(sc * (a0.w + 2.0f * h2f(hvu.w)));
    ((ushort4*)(yout + (size_t)vv * 64))[q] = r;
  }
}

// ---------------- contraction v4: C[g][j] = sum_v Y3[v][g] * x0[v][j] ----------------
// LDS-staged (r16 structure) + slab-level fp16->f32 conversion: x via
// global_load_lds (32KB), y reg-staged & converted ONCE per chunk into a
// 16KB f32 plane (16 h2f/thread/chunk vs 1024 in r16's inner loop).
// Inner loop: pure LDS-fed f32 FMA. 48KB LDS -> 3 blocks/CU.
#define CT_BLOCKS 768
#define CT_NCHUNK ((N_NODES + 63) / 64)   // 1563

__global__ __launch_bounds__(256) void k_contract(
    const float* __restrict__ x0, const unsigned short* __restrict__ y3,
    float* __restrict__ part) {
  __shared__ __align__(16) float xs[64 * 128];   // 32 KB
  __shared__ __align__(16) float ysf[64 * 64];   // 16 KB converted f32
  int t = threadIdx.x;
  int w = t >> 6;
  int lane = t & 63;
  int j = lane * 2;

  float2 acc[16];
#pragma unroll
  for (int i = 0; i < 16; i++) acc[i] = make_float2(0.f, 0.f);

  for (int c = blockIdx.x; c < CT_NCHUNK; c += gridDim.x) {
    int cc = min(64, N_NODES - c * 64);
    int bx = cc * 512;         // bytes of x slab (f32)
    int byh = cc * 128;        // bytes of y slab (fp16)
    const char* gx = (const char*)(x0 + (size_t)c * 64 * 128);
    const char* gy = (const char*)(y3 + (size_t)c * 64 * 64);
    __syncthreads();           // previous compute done before overwriting LDS
#pragma unroll
    for (int i = 0; i < 8; i++) {
      int off = i * 4096 + t * 16;
      if (off < bx) GLOAD_LDS16(gx + off, (char*)xs + off);
    }
    // y: reg-stage fp16 + convert once to f32 plane
    ushort4 u[4];
#pragma unroll
    for (int r = 0; r < 4; r++) {
      int off = (r * 256 + t) * 8;
      u[r] = (off < byh) ? *(const ushort4*)(gy + off)
                         : make_ushort4(0, 0, 0, 0);
    }
#pragma unroll
    for (int r = 0; r < 4; r++) {
      int idx = (r * 256 + t) * 4;       // f32 element index
      if (idx < cc * 64)
        *(float4*)(ysf + idx) = make_float4(h2f(u[r].x), h2f(u[r].y),
                                            h2f(u[r].z), h2f(u[r].w));
    }
    asm volatile("s_waitcnt vmcnt(0)" ::: "memory");
    __syncthreads();

    int v = 0;
    for (; v + 2 <= cc; v += 2) {
      float2 xa = *(const float2*)(xs + v * 128 + j);
      float2 xb = *(const float2*)(xs + (v + 1) * 128 + j);
      const float4* ya = (const float4*)(ysf + v * 64 + w * 16);
      const float4* yb = (const float4*)(ysf + (v + 1) * 64 + w * 16);
      float4 a0 = ya[0], a1 = ya[1], a2 = ya[2], a3 = ya[3];
      float4 b0 = yb[0], b1 = yb[1], b2 = yb[2], b3 = yb[3];
      float yas[16] = {a0.x, a0.y, a0.z, a0.w, a1.x, a1.y, a1.z, a1.w,
                       a2.x, a2.y, a2.z, a2.w, a3.x, a3.y, a3.z, a3.w};
      float ybs[16] = {b0.x, b0.y, b0.z, b0.w, b1.x, b1.y, b1.z, b1.w,
                       b2.x, b2.y, b2.z, b2.w, b3.x, b3.y, b3.z, b3.w};
#pragma unroll
      for (int i = 0; i < 16; i++) {
        acc[i].x += yas[i] * xa.x;
        acc[i].y += yas[i] * xa.y;
      }
#pragma unroll
      for (int i = 0; i < 16; i++) {
        acc[i].x += ybs[i] * xb.x;
        acc[i].y += ybs[i] * xb.y;
      }
    }
    if (v < cc) {
      float2 xa = *(const float2*)(xs + v * 128 + j);
      const float4* ya = (const float4*)(ysf + v * 64 + w * 16);
      float4 a0 = ya[0], a1 = ya[1], a2 = ya[2], a3 = ya[3];
      float yas[16] = {a0.x, a0.y, a0.z, a0.w, a1.x, a1.y, a1.z, a1.w,
                       a2.x, a2.y, a2.z, a2.w, a3.x, a3.y, a3.z, a3.w};
#pragma unroll
      for (int i = 0; i < 16; i++) {
        acc[i].x += yas[i] * xa.x;
        acc[i].y += yas[i] * xa.y;
      }
    }
  }

  float* dst = part + (size_t)blockIdx.x * (N_GRAPHS * WIDTH);
#pragma unroll
  for (int i = 0; i < 16; i++)
    *(float2*)(dst + (w * 16 + i) * WIDTH + j) = acc[i];
}

// ---------------- partials reduction: 768 rows -> 12 rows ----------------
#define RC_ROWS 64
#define RC_RG (CT_BLOCKS / RC_ROWS)   // 12

__global__ __launch_bounds__(256) void k_reduce1(
    const float* __restrict__ part, float* __restrict__ part2) {
  int bid = blockIdx.x, t = threadIdx.x;
  int rg = bid >> 5, colc = bid & 31;
  int idx = colc * 256 + t;
  const float* src = part + (size_t)rg * RC_ROWS * (N_GRAPHS * WIDTH) + idx;
  float a0 = 0.f, a1 = 0.f, a2 = 0.f, a3 = 0.f;
  for (int r = 0; r < RC_ROWS; r += 4) {
    a0 += src[(size_t)(r + 0) * (N_GRAPHS * WIDTH)];
    a1 += src[(size_t)(r + 1) * (N_GRAPHS * WIDTH)];
    a2 += src[(size_t)(r + 2) * (N_GRAPHS * WIDTH)];
    a3 += src[(size_t)(r + 3) * (N_GRAPHS * WIDTH)];
  }
  part2[rg * (N_GRAPHS * WIDTH) + idx] = (a0 + a1) + (a2 + a3);
}

// O = A*B (128x128 f32); block=row, thread=col
__global__ __launch_bounds__(WIDTH) void k_mm128(
    const float* __restrict__ A, const float* __restrict__ B, float* __restrict__ O) {
  __shared__ float Ar[WIDTH];
  int r = blockIdx.x, j = threadIdx.x;
  Ar[j] = A[r * WIDTH + j];
  __syncthreads();
  float a = 0.f;
#pragma unroll 8
  for (int k = 0; k < WIDTH; k++) a += Ar[k] * B[k * WIDTH + j];
  O[r * WIDTH + j] = a;
}

// c0 = b0^T * T1 ; c1 = b1^T * W2
__global__ __launch_bounds__(WIDTH) void k_c01(
    const float* __restrict__ b0, const float* __restrict__ T1,
    const float* __restrict__ b1, const float* __restrict__ W2,
    float* __restrict__ c0, float* __restrict__ c1) {
  __shared__ float s0[WIDTH], s1v[WIDTH];
  int j = threadIdx.x;
  s0[j] = b0[j]; s1v[j] = b1[j];
  __syncthreads();
  float a0 = 0.f, a1 = 0.f;
#pragma unroll 8
  for (int k = 0; k < WIDTH; k++) {
    a0 += s0[k] * T1[k * WIDTH + j];
    a1 += s1v[k] * W2[k * WIDTH + j];
  }
  c0[j] = a0; c1[j] = a1;
}

// out[g][j]: final 12-row C-sum fused in.
__global__ __launch_bounds__(WIDTH) void k_out(
    const float* __restrict__ part2, const float* __restrict__ Wp,
    const float* __restrict__ c0, const float* __restrict__ c1,
    const float* __restrict__ ps, const float* __restrict__ pas,
    const int* __restrict__ cntg, const float* __restrict__ b2,
    float* __restrict__ out) {
  __shared__ float Cr[WIDTH];
  int g = blockIdx.x, j = threadIdx.x;
  float cv = 0.f;
#pragma unroll
  for (int rg = 0; rg < RC_RG; rg++)
    cv += part2[rg * (N_GRAPHS * WIDTH) + g * WIDTH + j];
  Cr[j] = cv;
  __syncthreads();
  float a = pas[g] * c0[j] + ps[g] * c1[j] + ((cntg[g] > 0) ? b2[j] : 0.f);
#pragma unroll 8
  for (int k = 0; k < WIDTH; k++) a += Cr[k] * Wp[k * WIDTH + j];
  out[g * WIDTH + j] = a;
}

// ---------------- launch ----------------

extern "C" void kernel_launch(void* const* d_in, const int* in_sizes, int n_in,
                              void* d_out, int out_size, void* d_ws, size_t ws_size,
                              hipStream_t stream) {
  const float* x   = (const float*)d_in[0];
  const int* row   = (const int*)d_in[1];         // edge_index[0]
  const int* col   = row + N_EDGES;               // edge_index[1]
  const float* ew  = (const float*)d_in[2];
  const int* batch = (const int*)d_in[3];
  const float* Ws  = (const float*)d_in[4];
  const float* bs  = (const float*)d_in[5];
  float* out = (float*)d_out;

  char* w = (char*)d_ws;
  float* dinv    = (float*)(w + 0);
  float* d2      = (float*)(w + 400128);
  float* sq      = (float*)(w + 800256);
  float* deg     = (float*)(w + 1200384);
  int*   cursor  = (int*)(w + 1600512);
  int*   cntg    = (int*)(w + 2000640);
  float* invc    = (float*)(w + 2000896);
  float* ps      = (float*)(w + 2001152);
  float* pas     = (float*)(w + 2001408);
  float* T1      = (float*)(w + 2001664);
  float* Wp      = (float*)(w + 2067200);
  float* c0      = (float*)(w + 2132736);
  float* c1      = (float*)(w + 2133248);
  int2*  ell     = (int2*)(w + 2133760);     // 32 MB -> ends 34133760
  float* part    = (float*)(w + 34133760);   // 768*8192*4 = 25.2 MB
  float* part2   = (float*)(w + 67688192);   // 12*8192*4
  unsigned short* yA = (unsigned short*)(w + 68212480);  // N*64 fp16
  unsigned short* yB = (unsigned short*)(w + 81012480);  // N*64 fp16
  float* csA     = (float*)(w + 93812480);   // 512*64 f32
  float* csB     = (float*)(w + 93943552);   // ends 94074624

  int nb_n = (N_NODES + 255) / 256;
  int nb_e = (N_EDGES + 255) / 256;

  k_init   <<<nb_n, 256, 0, stream>>>(cursor, deg);
  k_fill_cd<<<nb_e, 256, 0, stream>>>(row, col, ew, cursor, deg, ell);
  k_dinv_e <<<nb_n, 256, 0, stream>>>(deg, dinv, d2, sq);

  k_cntg <<<1, 64, 0, stream>>>(batch, cntg, invc);
  k_pinit<<<2048, 256, 0, stream>>>(batch, invc, dinv, yA);

  int nb_y = (N_NODES + AGG_NPB - 1) / AGG_NPB;
  k_yagg  <<<nb_y, 256, 0, stream>>>(yA, cursor, ell, d2, yB);    // z1
  k_colsum<<<CS_BLOCKS, 256, 0, stream>>>(yB, sq, csA);           // -> ps partials
  k_yagg  <<<nb_y, 256, 0, stream>>>(yB, cursor, ell, d2, yA);    // z2
  k_colsum<<<CS_BLOCKS, 256, 0, stream>>>(yA, sq, csB);           // -> pas partials
  k_yagg  <<<nb_y, 256, 0, stream>>>(yA, cursor, ell, dinv, yB);  // y3 (true y)

  k_cs2  <<<2, 256, 0, stream>>>(csA, csB, ps, pas);
  k_mm128<<<WIDTH, WIDTH, 0, stream>>>(Ws + 1 * WIDTH * WIDTH, Ws + 2 * WIDTH * WIDTH, T1);
  k_mm128<<<WIDTH, WIDTH, 0, stream>>>(Ws + 0 * WIDTH * WIDTH, T1, Wp);
  k_c01  <<<1, WIDTH, 0, stream>>>(bs, T1, bs + WIDTH, Ws + 2 * WIDTH * WIDTH, c0, c1);

  k_contract<<<CT_BLOCKS, 256, 0, stream>>>(x, yB, part);
  k_reduce1 <<<RC_RG * 32, 256, 0, stream>>>(part, part2);
  k_out     <<<N_GRAPHS, WIDTH, 0, stream>>>(part2, Wp, c0, c1, ps, pas, cntg,
                                             bs + 2 * WIDTH, out);
}